// Round 1
// baseline (210.363 us; speedup 1.0000x reference)
//
#include <hip/hip_runtime.h>
#include <hip/hip_bf16.h>

typedef __attribute__((ext_vector_type(4))) float  f32x4;
typedef __attribute__((ext_vector_type(8))) short  bf16x8;

#define TOKENS    262144
#define DIM       256
#define TILE_TOK  128
#define NTILES    (TOKENS / TILE_TOK)   // 2048
#define NBLOCKS   256
#define NTHREADS  512
#define LDS_BYTES 131072                // 256 rows x 512 B (bf16 W, swizzled)

__device__ __forceinline__ short f2bf(float x) {
    __hip_bfloat16 h = __float2bfloat16(x);
    return *reinterpret_cast<short*>(&h);
}

// out[n][o] = sum_k X[n][k] * W0[o][k]   (expert 0 always selected)
__global__ __launch_bounds__(NTHREADS, 2)
void moe_expert0_kernel(const float* __restrict__ X,
                        const float* __restrict__ W0,
                        float* __restrict__ Out)
{
    extern __shared__ char lds[];
    const int tid = threadIdx.x;

    // ---- Stage W0 (256x256 fp32) -> bf16, XOR-swizzled, into LDS ----
    // addr(row, colbyte) = row*512 + (colbyte ^ ((row&15)<<4))
    #pragma unroll
    for (int i = 0; i < 16; ++i) {
        int chunk = tid + i * NTHREADS;   // 8-float chunk id, 8192 total
        int row = chunk >> 5;             // 32 chunks per 256-float row
        int c8  = chunk & 31;
        const f32x4* src = reinterpret_cast<const f32x4*>(W0 + row * DIM + c8 * 8);
        f32x4 f0 = src[0], f1 = src[1];
        bf16x8 w;
        w[0] = f2bf(f0[0]); w[1] = f2bf(f0[1]); w[2] = f2bf(f0[2]); w[3] = f2bf(f0[3]);
        w[4] = f2bf(f1[0]); w[5] = f2bf(f1[1]); w[6] = f2bf(f1[2]); w[7] = f2bf(f1[3]);
        int colbyte = c8 * 16;
        int addr = row * 512 + (colbyte ^ ((row & 15) << 4));
        *reinterpret_cast<bf16x8*>(lds + addr) = w;
    }
    __syncthreads();

    const int lane = tid & 63;
    const int wave = tid >> 6;
    const int cg   = wave & 3;    // channel group: 64 output chans
    const int tg   = wave >> 1 >> 1; // token group: 64 tokens (wave>>2)
    const int l15  = lane & 15;
    const int lg   = lane >> 4;   // 0..3 (k-subgroup)

    for (int tile = blockIdx.x; tile < NTILES; tile += gridDim.x) {
        const int tok0 = tile * TILE_TOK + tg * 64;
        const float* aptr = X + (size_t)(tok0 + l15) * DIM + lg * 8;

        // fp32 A staging, double-buffered one k-step ahead
        f32x4 abuf[2][4][2];
        #pragma unroll
        for (int mt = 0; mt < 4; ++mt) {
            const f32x4* p = reinterpret_cast<const f32x4*>(aptr + mt * 16 * DIM);
            abuf[0][mt][0] = p[0];
            abuf[0][mt][1] = p[1];
        }

        f32x4 acc[4][4];
        #pragma unroll
        for (int mt = 0; mt < 4; ++mt)
            #pragma unroll
            for (int nt = 0; nt < 4; ++nt)
                acc[mt][nt] = (f32x4)0.0f;

        #pragma unroll
        for (int s = 0; s < 8; ++s) {            // K = 256 = 8 steps x 32
            const int cur = s & 1, nxt = cur ^ 1;
            if (s < 7) {
                #pragma unroll
                for (int mt = 0; mt < 4; ++mt) {
                    const f32x4* p = reinterpret_cast<const f32x4*>(
                        aptr + mt * 16 * DIM + (s + 1) * 32);
                    abuf[nxt][mt][0] = p[0];
                    abuf[nxt][mt][1] = p[1];
                }
            }
            // B fragments from swizzled LDS (W rows = output chans, contiguous k)
            bf16x8 bfrag[4];
            #pragma unroll
            for (int nt = 0; nt < 4; ++nt) {
                int row = cg * 64 + nt * 16 + l15;
                int colbyte = s * 64 + lg * 16;
                int addr = row * 512 + (colbyte ^ ((row & 15) << 4));
                bfrag[nt] = *reinterpret_cast<const bf16x8*>(lds + addr);
            }
            // convert A fp32 -> bf16 fragments
            bf16x8 afrag[4];
            #pragma unroll
            for (int mt = 0; mt < 4; ++mt) {
                #pragma unroll
                for (int j = 0; j < 4; ++j) {
                    afrag[mt][j]     = f2bf(abuf[cur][mt][0][j]);
                    afrag[mt][j + 4] = f2bf(abuf[cur][mt][1][j]);
                }
            }
            #pragma unroll
            for (int mt = 0; mt < 4; ++mt)
                #pragma unroll
                for (int nt = 0; nt < 4; ++nt)
                    acc[mt][nt] = __builtin_amdgcn_mfma_f32_16x16x32_bf16(
                        afrag[mt], bfrag[nt], acc[mt][nt], 0, 0, 0);
        }

        // store 64x64 fp32 tile: C layout col=lane&15, row=(lane>>4)*4+reg
        #pragma unroll
        for (int mt = 0; mt < 4; ++mt) {
            #pragma unroll
            for (int nt = 0; nt < 4; ++nt) {
                #pragma unroll
                for (int r = 0; r < 4; ++r) {
                    int row = tok0 + mt * 16 + lg * 4 + r;
                    int col = cg * 64 + nt * 16 + l15;
                    Out[(size_t)row * DIM + col] = acc[mt][nt][r];
                }
            }
        }
        __syncthreads();   // bound wave drift so c-group A re-reads stay L1-hot
    }
}

extern "C" void kernel_launch(void* const* d_in, const int* in_sizes, int n_in,
                              void* d_out, int out_size, void* d_ws, size_t ws_size,
                              hipStream_t stream) {
    (void)in_sizes; (void)n_in; (void)d_ws; (void)ws_size; (void)out_size;
    const float* X = (const float*)d_in[0];
    const float* W = (const float*)d_in[1];   // [8,256,256]; expert 0 = first 65536
    float* Out = (float*)d_out;

    hipFuncSetAttribute((const void*)moe_expert0_kernel,
                        hipFuncAttributeMaxDynamicSharedMemorySize, LDS_BYTES);
    moe_expert0_kernel<<<dim3(NBLOCKS), dim3(NTHREADS), LDS_BYTES, stream>>>(X, W, Out);
}

// Round 2
// 181.839 us; speedup vs baseline: 1.1569x; 1.1569x over previous
//
#include <hip/hip_runtime.h>
#include <hip/hip_bf16.h>

typedef __attribute__((ext_vector_type(4))) float  f32x4;
typedef __attribute__((ext_vector_type(8))) short  bf16x8;

#define TOKENS    262144
#define DIM       256
#define TILE_TOK  128
#define NTILES    (TOKENS / TILE_TOK)     // 2048
#define NBLOCKS   256
#define NTHREADS  1024
#define TPB       (NTILES / NBLOCKS)      // 8 tiles per block
#define LDS_BYTES 131072                  // 256 rows x 512 B (bf16 W, swizzled)

__device__ __forceinline__ short f2bf(float x) {
    __hip_bfloat16 h = __float2bfloat16(x);
    return *reinterpret_cast<short*>(&h);
}

// Pinned-issue global load: compiler cannot sink this past the sched_barrier.
__device__ __forceinline__ f32x4 gload4(const float* p) {
    f32x4 r;
    asm volatile("global_load_dwordx4 %0, %1, off" : "=v"(r) : "v"(p) : "memory");
    return r;
}

// Issue one k-step's 4 dwordx4 loads (2 token-rows x 8 floats each half).
#define ISSUE(BUF, P, S) do {                      \
    BUF[0] = gload4((P) + (S)*32);                 \
    BUF[1] = gload4((P) + (S)*32 + 4);             \
    BUF[2] = gload4((P) + 16*DIM + (S)*32);        \
    BUF[3] = gload4((P) + 16*DIM + (S)*32 + 4);    \
} while (0)

// One k-step: prefetch next (stays in flight across the wait), wait for the
// current buffer (vmcnt(4) = all but the 4 just-issued), convert, LDS B, MFMA.
#define STEP(CUR, NXT, SC, PN, SN) do {                                        \
    ISSUE(NXT, PN, SN);                                                        \
    asm volatile("s_waitcnt vmcnt(4)" ::: "memory");                           \
    __builtin_amdgcn_sched_barrier(0);                                        \
    bf16x8 af0, af1;                                                           \
    _Pragma("unroll")                                                          \
    for (int j = 0; j < 4; ++j) {                                              \
        af0[j]   = f2bf(CUR[0][j]);  af0[j+4] = f2bf(CUR[1][j]);               \
        af1[j]   = f2bf(CUR[2][j]);  af1[j+4] = f2bf(CUR[3][j]);               \
    }                                                                          \
    bf16x8 bf_[4];                                                             \
    _Pragma("unroll")                                                          \
    for (int nt = 0; nt < 4; ++nt) {                                           \
        int baddr = bbase[nt] + ((((SC)*64) + lg*16) ^ bswz);                  \
        bf_[nt] = *reinterpret_cast<const bf16x8*>(lds + baddr);               \
    }                                                                          \
    _Pragma("unroll")                                                          \
    for (int nt = 0; nt < 4; ++nt) {                                           \
        acc0[nt] = __builtin_amdgcn_mfma_f32_16x16x32_bf16(af0, bf_[nt], acc0[nt], 0,0,0); \
        acc1[nt] = __builtin_amdgcn_mfma_f32_16x16x32_bf16(af1, bf_[nt], acc1[nt], 0,0,0); \
    }                                                                          \
} while (0)

// out[n][o] = sum_k X[n][k] * W0[o][k]   (router is degenerate: expert 0 always)
__global__ __launch_bounds__(NTHREADS, 4)
void moe_expert0_kernel(const float* __restrict__ X,
                        const float* __restrict__ W0,
                        float* __restrict__ Out)
{
    extern __shared__ char lds[];
    const int tid = threadIdx.x;

    // ---- Stage W0 (256x256 fp32) -> bf16, XOR-swizzled, into LDS (once) ----
    // addr(row, colbyte) = row*512 + (colbyte ^ ((row&15)<<4))
    #pragma unroll
    for (int i = 0; i < 8; ++i) {
        int chunk = tid + i * NTHREADS;   // 8-float chunk id, 8192 total
        int row = chunk >> 5;             // 32 chunks per 256-float row
        int c8  = chunk & 31;
        const f32x4* src = reinterpret_cast<const f32x4*>(W0 + row * DIM + c8 * 8);
        f32x4 f0 = src[0], f1 = src[1];
        bf16x8 w;
        w[0] = f2bf(f0[0]); w[1] = f2bf(f0[1]); w[2] = f2bf(f0[2]); w[3] = f2bf(f0[3]);
        w[4] = f2bf(f1[0]); w[5] = f2bf(f1[1]); w[6] = f2bf(f1[2]); w[7] = f2bf(f1[3]);
        int colbyte = c8 * 16;
        int addr = row * 512 + (colbyte ^ ((row & 15) << 4));
        *reinterpret_cast<bf16x8*>(lds + addr) = w;
    }
    __syncthreads();
    // W is read-only from here on: no further barriers, waves free-run.

    const int lane = tid & 63;
    const int wave = tid >> 6;
    const int cg   = wave & 3;    // channel group: 64 output chans
    const int tg   = wave >> 2;   // token group: 32 tokens within 128-token tile
    const int l15  = lane & 15;
    const int lg   = lane >> 4;   // k-subgroup 0..3

    // B fragment addressing (row & 15 == l15 for all nt, so swz term is l15<<4)
    int bbase[4];
    #pragma unroll
    for (int nt = 0; nt < 4; ++nt)
        bbase[nt] = (cg * 64 + nt * 16 + l15) * 512;
    const int bswz = l15 << 4;

    const size_t blockStride = (size_t)NBLOCKS * TILE_TOK * DIM;  // floats
    const float* ap = X + (size_t)(blockIdx.x * TILE_TOK + tg * 32 + l15) * DIM + lg * 8;
    float*       op = Out + (size_t)(blockIdx.x * TILE_TOK + tg * 32 + lg * 4) * DIM
                          + cg * 64 + l15;

    f32x4 A0[4], A1[4];
    ISSUE(A0, ap, 0);   // prologue: tile 0, k-step 0

    for (int t = 0; t < TPB; ++t) {
        const float* apc = ap;
        const float* apn = (t + 1 < TPB) ? ap + blockStride : ap;  // wrap: harmless
        f32x4 acc0[4], acc1[4];
        #pragma unroll
        for (int nt = 0; nt < 4; ++nt) { acc0[nt] = (f32x4)0.0f; acc1[nt] = (f32x4)0.0f; }

        STEP(A0, A1, 0, apc, 1);
        STEP(A1, A0, 1, apc, 2);
        STEP(A0, A1, 2, apc, 3);
        STEP(A1, A0, 3, apc, 4);
        STEP(A0, A1, 4, apc, 5);
        STEP(A1, A0, 5, apc, 6);
        STEP(A0, A1, 6, apc, 7);
        STEP(A1, A0, 7, apn, 0);   // prefetch next tile's k-step 0

        // store 32x64 fp32 sub-tile: C layout col=lane&15, row=(lane>>4)*4+reg
        #pragma unroll
        for (int nt = 0; nt < 4; ++nt) {
            #pragma unroll
            for (int r = 0; r < 4; ++r) {
                op[(size_t)(r)      * DIM + nt * 16] = acc0[nt][r];
                op[(size_t)(16 + r) * DIM + nt * 16] = acc1[nt][r];
            }
        }

        ap  = apn;
        op += blockStride;
    }
}

extern "C" void kernel_launch(void* const* d_in, const int* in_sizes, int n_in,
                              void* d_out, int out_size, void* d_ws, size_t ws_size,
                              hipStream_t stream) {
    (void)in_sizes; (void)n_in; (void)d_ws; (void)ws_size; (void)out_size;
    const float* X = (const float*)d_in[0];
    const float* W = (const float*)d_in[1];   // [8,256,256]; expert 0 = first 65536
    float* Out = (float*)d_out;

    hipFuncSetAttribute((const void*)moe_expert0_kernel,
                        hipFuncAttributeMaxDynamicSharedMemorySize, LDS_BYTES);
    moe_expert0_kernel<<<dim3(NBLOCKS), dim3(NTHREADS), LDS_BYTES, stream>>>(X, W, Out);
}

// Round 3
// 138.594 us; speedup vs baseline: 1.5178x; 1.3120x over previous
//
#include <hip/hip_runtime.h>
#include <hip/hip_bf16.h>

typedef __attribute__((ext_vector_type(4))) float  f32x4;
typedef __attribute__((ext_vector_type(8))) short  bf16x8;

#define DIM       256
#define TILE_TOK  256
#define NBLOCKS   256
#define NTHREADS  1024
#define TPB       8            // tiles per (stream,half)
#define XOFF      65536        // W half occupies [0, 64 KB)
#define XBUFSZ    32768        // 256 rows x 128 B fp32 k-slice
#define LDS_BYTES 131072

__device__ __forceinline__ short f2bf(float x) {
    __hip_bfloat16 h = __float2bfloat16(x);
    return *reinterpret_cast<short*>(&h);
}

__device__ __forceinline__ void gload_lds16(const float* g, char* l) {
    __builtin_amdgcn_global_load_lds(
        (const __attribute__((address_space(1))) void*)g,
        (__attribute__((address_space(3))) void*)l, 16, 0, 0);
}

// Stage one 32-KB X k-slice (256 tok x 32 k fp32) into buffer C.
// LDS dest is linear (wave-uniform base + lane*16); the XOR swizzle is applied
// to the per-lane GLOBAL source column (both-sides-or-neither, G21).
#define STAGE(C, BASE, KS) do {                                                \
    _Pragma("unroll")                                                          \
    for (int i_ = 0; i_ < 2; ++i_) {                                           \
        int seg_ = wave * 2 + i_;                                              \
        const float* g_ = X + (size_t)((BASE) + seg_ * 8 + rowInSeg) * DIM     \
                            + (KS) * 32 + srcColF;                             \
        gload_lds16(g_, lds + XOFF + (C) * XBUFSZ + seg_ * 1024);              \
    }                                                                          \
} while (0)

// out[n][o] = sum_k X[n][k] * W0[o][k]  (router is degenerate: expert 0 always)
__global__ __launch_bounds__(NTHREADS, 4)
void moe_expert0_kernel(const float* __restrict__ X,
                        const float* __restrict__ W0,
                        float* __restrict__ Out)
{
    extern __shared__ char lds[];
    const int tid  = threadIdx.x;
    const int lane = tid & 63;
    const int wave = tid >> 6;
    const int b    = blockIdx.x;

    // b and b^8 share (stream u) and sit on the same XCD (b%8): the two
    // chan-halves of each token tile share X through the XCD's L2.
    const int half = (b >> 3) & 1;
    const int u    = (b & 7) * 16 + (b >> 4);   // 0..127, bijective

    // ---- stage W half (128 out-chans x 256 k) -> bf16, XOR-swizzled ----
    // addr(row, colbyte) = row*512 + (colbyte ^ ((row&15)<<4))
    const float* Wh = W0 + (size_t)half * 128 * DIM;
    #pragma unroll
    for (int i = 0; i < 4; ++i) {
        int chunk = tid + i * NTHREADS;   // 4096 chunks of 8 floats
        int row = chunk >> 5;
        int c8  = chunk & 31;
        const f32x4* src = reinterpret_cast<const f32x4*>(Wh + row * DIM + c8 * 8);
        f32x4 f0 = src[0], f1 = src[1];
        bf16x8 w;
        w[0] = f2bf(f0[0]); w[1] = f2bf(f0[1]); w[2] = f2bf(f0[2]); w[3] = f2bf(f0[3]);
        w[4] = f2bf(f1[0]); w[5] = f2bf(f1[1]); w[6] = f2bf(f1[2]); w[7] = f2bf(f1[3]);
        int addr = row * 512 + ((c8 * 16) ^ ((row & 15) << 4));
        *reinterpret_cast<bf16x8*>(lds + addr) = w;
    }

    const int l15 = lane & 15;
    const int lg  = lane >> 4;     // k-subgroup 0..3
    const int cg  = wave & 1;      // 64-chan group within the 128-chan half
    const int tg  = wave >> 1;     // 32-token group 0..7

    // X staging constants (pre-swizzled source, G21 involution)
    const int rowInSeg = lane >> 3;                                  // 0..7
    const int srcColF  = ((((lane & 7) * 16) ^ ((lane >> 3) << 4)) >> 2);

    // A-read addressing: row r => byte r*128 + (colbyte ^ ((r&7)<<4))
    const int r0off = (tg * 32 + l15) * 128;
    const int swA   = (l15 & 7) << 4;

    // B-read addressing (row&15 == l15)
    int bbase[4];
    #pragma unroll
    for (int nt = 0; nt < 4; ++nt)
        bbase[nt] = (cg * 64 + nt * 16 + l15) * 512;
    const int bswz = l15 << 4;

    // prologue: first tile, k-step 0 into buffer 0 (barrier also covers W stage)
    STAGE(0, (size_t)u * TILE_TOK, 0);
    __syncthreads();

    for (int t = 0; t < TPB; ++t) {
        const size_t tokbase = (size_t)(u + 128 * t) * TILE_TOK;
        const size_t toknext = tokbase + (size_t)128 * TILE_TOK;

        f32x4 acc[2][4];
        #pragma unroll
        for (int mt = 0; mt < 2; ++mt)
            #pragma unroll
            for (int nt = 0; nt < 4; ++nt)
                acc[mt][nt] = (f32x4)0.0f;

        #pragma unroll
        for (int s = 0; s < 8; ++s) {
            if (s < 7)            STAGE((s + 1) & 1, tokbase, s + 1);
            else if (t + 1 < TPB) STAGE(0, toknext, 0);

            const char* xb = lds + XOFF + (s & 1) * XBUFSZ;
            f32x4 a00 = *reinterpret_cast<const f32x4*>(xb + r0off +        ((lg * 32)      ^ swA));
            f32x4 a01 = *reinterpret_cast<const f32x4*>(xb + r0off +        ((lg * 32 + 16) ^ swA));
            f32x4 a10 = *reinterpret_cast<const f32x4*>(xb + r0off + 2048 + ((lg * 32)      ^ swA));
            f32x4 a11 = *reinterpret_cast<const f32x4*>(xb + r0off + 2048 + ((lg * 32 + 16) ^ swA));

            bf16x8 bfr[4];
            #pragma unroll
            for (int nt = 0; nt < 4; ++nt)
                bfr[nt] = *reinterpret_cast<const bf16x8*>(
                    lds + bbase[nt] + ((s * 64 + lg * 16) ^ bswz));

            bf16x8 af0, af1;
            #pragma unroll
            for (int j = 0; j < 4; ++j) {
                af0[j]     = f2bf(a00[j]);
                af0[j + 4] = f2bf(a01[j]);
                af1[j]     = f2bf(a10[j]);
                af1[j + 4] = f2bf(a11[j]);
            }

            #pragma unroll
            for (int nt = 0; nt < 4; ++nt) {
                acc[0][nt] = __builtin_amdgcn_mfma_f32_16x16x32_bf16(af0, bfr[nt], acc[0][nt], 0, 0, 0);
                acc[1][nt] = __builtin_amdgcn_mfma_f32_16x16x32_bf16(af1, bfr[nt], acc[1][nt], 0, 0, 0);
            }

            __syncthreads();   // drains this wave's stage loads + all LDS reads
        }

        // store 32x128 sub-tile: C layout col=lane&15, row=(lane>>4)*4+reg
        #pragma unroll
        for (int mt = 0; mt < 2; ++mt) {
            #pragma unroll
            for (int nt = 0; nt < 4; ++nt) {
                #pragma unroll
                for (int r = 0; r < 4; ++r) {
                    size_t row = tokbase + tg * 32 + mt * 16 + lg * 4 + r;
                    int    col = half * 128 + cg * 64 + nt * 16 + l15;
                    Out[row * DIM + col] = acc[mt][nt][r];
                }
            }
        }
    }
}

extern "C" void kernel_launch(void* const* d_in, const int* in_sizes, int n_in,
                              void* d_out, int out_size, void* d_ws, size_t ws_size,
                              hipStream_t stream) {
    (void)in_sizes; (void)n_in; (void)d_ws; (void)ws_size; (void)out_size;
    const float* X = (const float*)d_in[0];
    const float* W = (const float*)d_in[1];   // [8,256,256]; expert 0 = first 65536
    float* Out = (float*)d_out;

    hipFuncSetAttribute((const void*)moe_expert0_kernel,
                        hipFuncAttributeMaxDynamicSharedMemorySize, LDS_BYTES);
    moe_expert0_kernel<<<dim3(NBLOCKS), dim3(NTHREADS), LDS_BYTES, stream>>>(X, W, Out);
}

// Round 4
// 120.133 us; speedup vs baseline: 1.7511x; 1.1537x over previous
//
#include <hip/hip_runtime.h>
#include <hip/hip_bf16.h>

typedef __attribute__((ext_vector_type(4))) float  f32x4;
typedef __attribute__((ext_vector_type(8))) short  bf16x8;

#define DIM       256
#define TILE_TOK  128
#define NBLOCKS   256
#define NTHREADS  1024
#define TPB       16           // token tiles per block
#define XOFF      65536        // W half occupies [0, 64 KB)
#define XBUFSZ    16384        // 128 tok x 128 B fp32 k-slice
#define LDS_BYTES 131072

#define WAITV(N) asm volatile("s_waitcnt vmcnt(" #N ")" ::: "memory")

__device__ __forceinline__ short f2bf(float x) {
    __hip_bfloat16 h = __float2bfloat16(x);
    return *reinterpret_cast<short*>(&h);
}

__device__ __forceinline__ void gload_lds16(const float* g, char* l) {
    __builtin_amdgcn_global_load_lds(
        (const __attribute__((address_space(1))) void*)g,
        (__attribute__((address_space(3))) void*)l, 16, 0, 0);
}

// out[n][o] = sum_k X[n][k] * W0[o][k]  (router is degenerate: expert 0 always)
__global__ __launch_bounds__(NTHREADS, 4)
void moe_expert0_kernel(const float* __restrict__ X,
                        const float* __restrict__ W0,
                        float* __restrict__ Out)
{
    extern __shared__ char lds[];
    const int tid  = threadIdx.x;
    const int lane = tid & 63;
    const int wave = tid >> 6;
    const int b    = blockIdx.x;

    // b and b^8 share token-stream u and sit on the same XCD (b&7): the two
    // chan-halves of each token tile share X through that XCD's L2.
    const int half = (b >> 3) & 1;
    const int u    = (b & 7) * 16 + (b >> 4);   // 0..127, bijective

    // ---- stage W half (128 out-chans x 256 k) -> bf16, XOR-swizzled ----
    // addr(row, colbyte) = row*512 + (colbyte ^ ((row&15)<<4))
    const float* Wh = W0 + (size_t)half * 128 * DIM;
    #pragma unroll
    for (int i = 0; i < 4; ++i) {
        int chunk = tid + i * NTHREADS;   // 4096 chunks of 8 floats
        int row = chunk >> 5;
        int c8  = chunk & 31;
        const f32x4* src = reinterpret_cast<const f32x4*>(Wh + row * DIM + c8 * 8);
        f32x4 f0 = src[0], f1 = src[1];
        bf16x8 w;
        w[0] = f2bf(f0[0]); w[1] = f2bf(f0[1]); w[2] = f2bf(f0[2]); w[3] = f2bf(f0[3]);
        w[4] = f2bf(f1[0]); w[5] = f2bf(f1[1]); w[6] = f2bf(f1[2]); w[7] = f2bf(f1[3]);
        int addr = row * 512 + ((c8 * 16) ^ ((row & 15) << 4));
        *reinterpret_cast<bf16x8*>(lds + addr) = w;
    }

    const int l15 = lane & 15;
    const int lg  = lane >> 4;     // k-subgroup 0..3
    const int cg  = wave & 1;      // 64-chan group within the 128-chan half
    const int tg  = wave >> 1;     // 16-token group 0..7

    // X staging constants (pre-swizzled global source, G21 involution):
    // LDS[row][cb] = X[row][cb ^ ((row&7)<<4)]
    const int rowseg  = lane >> 3;                                   // 0..7
    const int srcColF = ((((lane & 7) * 16) ^ (rowseg << 4)) >> 2);

    // A-read: row r -> byte r*128 + (colbyte ^ ((r&7)<<4))
    const int arow = (tg * 16 + l15) * 128;
    const int swA  = (l15 & 7) << 4;

    // B-read (row & 15 == l15)
    int bbase[4];
    #pragma unroll
    for (int nt = 0; nt < 4; ++nt)
        bbase[nt] = (cg * 64 + nt * 16 + l15) * 512;
    const int bswz = l15 << 4;

    // ---- prologue: stage (t0,s0)->buf0, (t0,s1)->buf1; drain W ds_writes ----
    {
        const float* g0 = X + (size_t)((u) * TILE_TOK + wave * 8 + rowseg) * DIM + srcColF;
        gload_lds16(g0, lds + XOFF + 0 * XBUFSZ + wave * 1024);
        const float* g1 = g0 + 32;
        gload_lds16(g1, lds + XOFF + 1 * XBUFSZ + wave * 1024);
    }
    asm volatile("s_waitcnt lgkmcnt(0)" ::: "memory");

    for (int t = 0; t < TPB; ++t) {
        const size_t tokbase = (size_t)(u + 128 * t) * TILE_TOK;

        f32x4 acc[4];
        #pragma unroll
        for (int nt = 0; nt < 4; ++nt) acc[nt] = (f32x4)0.0f;

        #pragma unroll
        for (int s = 0; s < 8; ++s) {
            // stage k-step (step+2); buffer ring index = (s+2)&3 (8t == 0 mod 4)
            {
                const int s2 = (s + 2) & 7;
                const int t2 = (t + (s >= 6 ? 1 : 0)) & 15;   // tail wraps, data unused
                const float* g_ = X + (size_t)((u + 128 * t2) * TILE_TOK + wave * 8 + rowseg) * DIM
                                    + s2 * 32 + srcColF;
                gload_lds16(g_, lds + XOFF + ((s + 2) & 3) * XBUFSZ + wave * 1024);
            }
            // counted wait: own stage(step) complete. In flight: 2 stages,
            // plus the 16 C-stores at tile boundaries (s==0,1 when t>0).
            if (s <= 1) { if (t) { WAITV(18); } else { WAITV(2); } }
            else        { WAITV(2); }
            __builtin_amdgcn_s_barrier();
            __builtin_amdgcn_sched_barrier(0);

            const char* xb = lds + XOFF + (s & 3) * XBUFSZ;
            f32x4 a00 = *reinterpret_cast<const f32x4*>(xb + arow + ((lg * 32)      ^ swA));
            f32x4 a01 = *reinterpret_cast<const f32x4*>(xb + arow + ((lg * 32 + 16) ^ swA));

            bf16x8 bfr[4];
            #pragma unroll
            for (int nt = 0; nt < 4; ++nt)
                bfr[nt] = *reinterpret_cast<const bf16x8*>(
                    lds + bbase[nt] + ((s * 64 + lg * 16) ^ bswz));

            bf16x8 af;
            #pragma unroll
            for (int j = 0; j < 4; ++j) {
                af[j]     = f2bf(a00[j]);
                af[j + 4] = f2bf(a01[j]);
            }

            #pragma unroll
            for (int nt = 0; nt < 4; ++nt)
                acc[nt] = __builtin_amdgcn_mfma_f32_16x16x32_bf16(af, bfr[nt], acc[nt], 0, 0, 0);
        }

        // store 16x64 sub-tile: C layout col=lane&15, row=(lane>>4)*4+reg
        #pragma unroll
        for (int nt = 0; nt < 4; ++nt) {
            #pragma unroll
            for (int r = 0; r < 4; ++r) {
                size_t row = tokbase + tg * 16 + lg * 4 + r;
                int    col = half * 128 + cg * 64 + nt * 16 + l15;
                Out[row * DIM + col] = acc[nt][r];
            }
        }
    }
}

extern "C" void kernel_launch(void* const* d_in, const int* in_sizes, int n_in,
                              void* d_out, int out_size, void* d_ws, size_t ws_size,
                              hipStream_t stream) {
    (void)in_sizes; (void)n_in; (void)d_ws; (void)ws_size; (void)out_size;
    const float* X = (const float*)d_in[0];
    const float* W = (const float*)d_in[1];   // [8,256,256]; expert 0 = first 65536
    float* Out = (float*)d_out;

    hipFuncSetAttribute((const void*)moe_expert0_kernel,
                        hipFuncAttributeMaxDynamicSharedMemorySize, LDS_BYTES);
    moe_expert0_kernel<<<dim3(NBLOCKS), dim3(NTHREADS), LDS_BYTES, stream>>>(X, W, Out);
}

// Round 5
// 118.629 us; speedup vs baseline: 1.7733x; 1.0127x over previous
//
#include <hip/hip_runtime.h>
#include <hip/hip_bf16.h>

typedef __attribute__((ext_vector_type(4))) float  f32x4;
typedef __attribute__((ext_vector_type(8))) short  bf16x8;
typedef __attribute__((ext_vector_type(4))) short  bf16x4;

#define DIM       256
#define TILE_TOK  128
#define NBLOCKS   256
#define NTHREADS  1024
#define TPB       8              // token tiles per block (2048/256)
#define NSLICE    (TPB * 8)      // 64 k-slices per block
#define XOFF      131072         // W bf16 swizzled occupies [0, 128 KB)
#define XSLICE    8192           // one X slice: 128 tok x 64 B bf16
#define LDS_BYTES 163840         // 128K W + 4-slot X ring = 160 KB exactly

#define WAITV(N) asm volatile("s_waitcnt vmcnt(" #N ")" ::: "memory")

__device__ __forceinline__ short f2bf(float x) {
    __hip_bfloat16 h = __float2bfloat16(x);
    return *reinterpret_cast<short*>(&h);
}

// Pinned-issue global load (compiler inserts no vmcnt for asm loads: WAITV +
// sched_barrier(0) before any use of the result — rule 18).
__device__ __forceinline__ f32x4 gload4(const float* p) {
    f32x4 r;
    asm volatile("global_load_dwordx4 %0, %1, off" : "=v"(r) : "v"(p) : "memory");
    return r;
}

// out[n][o] = sum_k X[n][k] * W0[o][k]  (router is degenerate: expert 0 always)
__global__ __launch_bounds__(NTHREADS, 4)
void moe_expert0_kernel(const float* __restrict__ X,
                        const float* __restrict__ W0,
                        float* __restrict__ Out)
{
    extern __shared__ char lds[];
    const int tid  = threadIdx.x;
    const int lane = tid & 63;
    const int wave = tid >> 6;
    const int b    = blockIdx.x;

    // ---- stage full W (256x256) -> bf16, XOR-swizzled: row*512 + (cb ^ ((row&15)<<4))
    #pragma unroll
    for (int i = 0; i < 8; ++i) {
        int chunk = tid + i * NTHREADS;   // 8192 chunks of 8 floats
        int row = chunk >> 5;
        int c8  = chunk & 31;
        const f32x4* src = reinterpret_cast<const f32x4*>(W0 + row * DIM + c8 * 8);
        f32x4 f0 = src[0], f1 = src[1];
        bf16x8 w;
        w[0] = f2bf(f0[0]); w[1] = f2bf(f0[1]); w[2] = f2bf(f0[2]); w[3] = f2bf(f0[3]);
        w[4] = f2bf(f1[0]); w[5] = f2bf(f1[1]); w[6] = f2bf(f1[2]); w[7] = f2bf(f1[3]);
        int addr = row * 512 + ((c8 * 16) ^ ((row & 15) << 4));
        *reinterpret_cast<bf16x8*>(lds + addr) = w;
    }
    WAITV(0);   // drain W loads so asm-load vmcnt counting below is exact

    const int l15 = lane & 15;
    const int lg  = lane >> 4;     // k-subgroup 0..3
    const int cg  = wave & 1;      // 128-chan half
    const int tg  = wave >> 1;     // 16-token group 0..7

    // X staging lanes: row = wave*8 + (lane>>3), k-col = (lane&7)*4 (fp32)
    const int xrow = wave * 8 + (lane >> 3);
    const int xcol = (lane & 7) * 4;
    // bf16 ds_write offset within slice: row*64 + (lane&7)*8
    const int dswoff = xrow * 64 + (lane & 7) * 8;

    // A-read (X slice): row = tg*16+l15, 16B at colbyte lg*16 (quad-uniform, no swz)
    const int arow = (tg * 16 + l15) * 64 + lg * 16;
    // B-read (W): row = cg*128 + nt*16 + l15; swizzle term depends only on l15
    const int bbase = (cg * 128 + l15) * 512;
    const int bswz  = l15 << 4;

    const float* Xblk = X + (size_t)b * 1024 * DIM;
    #define GADDR(Q) (Xblk + (size_t)(((Q) >> 3) * TILE_TOK + xrow) * DIM + ((Q) & 7) * 32 + xcol)

    f32x4 X4[4];

    // ---- prologue: slices 0..2 staged; glb(3), glb(4) in flight ----
    X4[0] = gload4(GADDR(0));
    X4[1] = gload4(GADDR(1));
    X4[2] = gload4(GADDR(2));

    WAITV(2); __builtin_amdgcn_sched_barrier(0);
    { bf16x4 xw; xw[0]=f2bf(X4[0][0]); xw[1]=f2bf(X4[0][1]); xw[2]=f2bf(X4[0][2]); xw[3]=f2bf(X4[0][3]);
      *reinterpret_cast<bf16x4*>(lds + XOFF + 0 * XSLICE + dswoff) = xw; }
    X4[3] = gload4(GADDR(3));

    WAITV(2); __builtin_amdgcn_sched_barrier(0);
    { bf16x4 xw; xw[0]=f2bf(X4[1][0]); xw[1]=f2bf(X4[1][1]); xw[2]=f2bf(X4[1][2]); xw[3]=f2bf(X4[1][3]);
      *reinterpret_cast<bf16x4*>(lds + XOFF + 1 * XSLICE + dswoff) = xw; }
    X4[0] = gload4(GADDR(4));

    WAITV(2); __builtin_amdgcn_sched_barrier(0);
    { bf16x4 xw; xw[0]=f2bf(X4[2][0]); xw[1]=f2bf(X4[2][1]); xw[2]=f2bf(X4[2][2]); xw[3]=f2bf(X4[2][3]);
      *reinterpret_cast<bf16x4*>(lds + XOFF + 2 * XSLICE + dswoff) = xw; }

    asm volatile("s_waitcnt lgkmcnt(0)" ::: "memory");
    __builtin_amdgcn_s_barrier();

    for (int t = 0; t < TPB; ++t) {
        f32x4 acc[8];
        #pragma unroll
        for (int nt = 0; nt < 8; ++nt) acc[nt] = (f32x4)0.0f;

        #pragma unroll
        for (int s = 0; s < 8; ++s) {
            const int q = t * 8 + s;

            // 1. issue glb(q+5) into reg slot (s+5)&3 (addr-clamped at tail)
            { int qg = q + 5; if (qg > NSLICE - 1) qg = NSLICE - 1;
              X4[(s + 5) & 3] = gload4(GADDR(qg)); }

            // 2. compute step s from ring slot s&3
            {
                const char* xb = lds + XOFF + (s & 3) * XSLICE;
                bf16x8 af = *reinterpret_cast<const bf16x8*>(xb + arow);
                #pragma unroll
                for (int nt = 0; nt < 8; ++nt) {
                    bf16x8 bfr = *reinterpret_cast<const bf16x8*>(
                        lds + bbase + nt * 16 * 512 + ((s * 64 + lg * 16) ^ bswz));
                    acc[nt] = __builtin_amdgcn_mfma_f32_16x16x32_bf16(bfr, af, acc[nt], 0, 0, 0);
                }
            }

            // 3. wait for glb(q+3): 2 newer glbs outstanding; at the two steps
            //    after a tile boundary the 8 C-stores sit between them -> 10.
            if (t > 0 && s < 2) { WAITV(10); } else { WAITV(2); }
            __builtin_amdgcn_sched_barrier(0);

            // 4. cvt + ds_write slice q+3 into ring slot (s+3)&3
            {
                f32x4 xv = X4[(s + 3) & 3];
                bf16x4 xw;
                xw[0] = f2bf(xv[0]); xw[1] = f2bf(xv[1]);
                xw[2] = f2bf(xv[2]); xw[3] = f2bf(xv[3]);
                *reinterpret_cast<bf16x4*>(lds + XOFF + ((s + 3) & 3) * XSLICE + dswoff) = xw;
            }

            // 5. C stores (float4: 4 consecutive chans per lane, swapped-operand D)
            if (s == 7) {
                float* o = Out + (size_t)(b * 1024 + t * TILE_TOK + tg * 16 + l15) * DIM
                               + cg * 128 + lg * 4;
                #pragma unroll
                for (int nt = 0; nt < 8; ++nt)
                    *reinterpret_cast<f32x4*>(o + nt * 16) = acc[nt];
            }

            asm volatile("s_waitcnt lgkmcnt(0)" ::: "memory");
            __builtin_amdgcn_s_barrier();
        }
    }
    #undef GADDR
}

extern "C" void kernel_launch(void* const* d_in, const int* in_sizes, int n_in,
                              void* d_out, int out_size, void* d_ws, size_t ws_size,
                              hipStream_t stream) {
    (void)in_sizes; (void)n_in; (void)d_ws; (void)ws_size; (void)out_size;
    const float* X = (const float*)d_in[0];
    const float* W = (const float*)d_in[1];   // [8,256,256]; expert 0 = first 65536
    float* Out = (float*)d_out;

    hipFuncSetAttribute((const void*)moe_expert0_kernel,
                        hipFuncAttributeMaxDynamicSharedMemorySize, LDS_BYTES);
    moe_expert0_kernel<<<dim3(NBLOCKS), dim3(NTHREADS), LDS_BYTES, stream>>>(X, W, Out);
}